// Round 1
// baseline (4923.515 us; speedup 1.0000x reference)
//
#include <hip/hip_runtime.h>
#include <cstdint>
#include <cmath>

#define H 64
#define NFEAT 32
#define NNHID 128

static __device__ __forceinline__ float sigmoidf_(float x) { return 1.f / (1.f + expf(-x)); }

// ---------------- generic fill ----------------
__global__ void fill_u32_k(uint32_t* __restrict__ p, uint32_t v, long long n) {
  long long i = (long long)blockIdx.x * blockDim.x + threadIdx.x;
  long long stride = (long long)gridDim.x * blockDim.x;
  for (; i < n; i += stride) p[i] = v;
}

// ---------------- degree ----------------
__global__ void count_deg_k(const int* __restrict__ dst, float* __restrict__ deg, int E) {
  int i = blockIdx.x * 256 + threadIdx.x;
  if (i < E) atomicAdd(&deg[dst[i]], 1.f);
}
__global__ void inv_deg_k(float* __restrict__ deg, int n) {
  int i = blockIdx.x * 256 + threadIdx.x;
  if (i < n) deg[i] = 1.f / fmaxf(deg[i], 1.f);
}

// ---------------- lin0: out = relu(x @ w + b), x[N][32], w[32][64] ----------------
__global__ __launch_bounds__(256) void lin0_k(const float* __restrict__ x,
    const float* __restrict__ w, const float* __restrict__ b,
    float* __restrict__ out, int n) {
  __shared__ float xr[4][NFEAT];
  int t = threadIdx.x;
  int nodeblk = blockIdx.x * 4;
  if (t < 4 * NFEAT) {
    int nn = nodeblk + t / NFEAT;
    xr[t / NFEAT][t % NFEAT] = (nn < n) ? x[(size_t)nn * NFEAT + (t % NFEAT)] : 0.f;
  }
  __syncthreads();
  int node = nodeblk + t / H;
  int c = t % H;
  if (node >= n) return;
  float acc = b[c];
  #pragma unroll
  for (int j = 0; j < NFEAT; ++j) acc += xr[t / H][j] * w[j * H + c];
  out[(size_t)node * H + c] = fmaxf(acc, 0.f);
}

// ------------- edge MLP layer1 (relu(ea @ w1 + b1)) -> transposed uT[128][E] -------------
__global__ __launch_bounds__(128) void edge_mlp1_k(const float* __restrict__ ea,
    const float* __restrict__ w1, const float* __restrict__ b1,
    float* __restrict__ uT, int E) {
  __shared__ float ar[64][H];        // [edge][j]  16 KB
  __shared__ float ut[NNHID][65];    // [k][e] padded  33.3 KB
  int t = threadIdx.x;
  int e0 = blockIdx.x * 64;
  #pragma unroll
  for (int p = 0; p < 32; ++p) {
    int idx = p * 128 + t;
    int e = idx >> 6, j = idx & 63;
    ar[e][j] = (e0 + e < E) ? ea[(size_t)(e0 + e) * H + j] : 0.f;
  }
  __syncthreads();
  float bb = b1[t];
  for (int et = 0; et < 64; et += 16) {
    float acc[16];
    #pragma unroll
    for (int q = 0; q < 16; ++q) acc[q] = bb;
    #pragma unroll
    for (int j = 0; j < H; ++j) {
      float wv = w1[j * NNHID + t];
      #pragma unroll
      for (int q = 0; q < 16; ++q) acc[q] += ar[et + q][j] * wv;
    }
    #pragma unroll
    for (int q = 0; q < 16; ++q) ut[t][et + q] = fmaxf(acc[q], 0.f);
  }
  __syncthreads();
  int ecol = t & 63;
  int krow0 = t >> 6;  // 0 or 1
  if (e0 + ecol < E) {
    for (int p = 0; p < 64; ++p) {
      int k = p * 2 + krow0;
      uT[(size_t)k * E + e0 + ecol] = ut[k][ecol];
    }
  }
}

// ------- W GEMM: W[le][c] = sum_k u[e0+le][k]*w2[k][c] + b2[c]; tile 128x128, K=128 -------
__global__ __launch_bounds__(256) void gemm_w_k(const float* __restrict__ uT,
    const float* __restrict__ w2, const float* __restrict__ b2,
    float* __restrict__ W, int E, int e0, int ce) {
  __shared__ float a_lds[64][128];  // [k][e] 32 KB
  __shared__ float b_lds[64][128];  // [k][c] 32 KB
  int t = threadIdx.x;
  int be = blockIdx.x * 128;
  int bc = blockIdx.y * 128;
  int tx = t & 15, ty = t >> 4;
  float acc[8][8];
  #pragma unroll
  for (int i = 0; i < 8; ++i)
    #pragma unroll
    for (int j = 0; j < 8; ++j) acc[i][j] = 0.f;
  for (int k0 = 0; k0 < NNHID; k0 += 64) {
    #pragma unroll
    for (int p = 0; p < 8; ++p) {
      int q = p * 256 + t;
      int k = q >> 5;
      int c4 = (q & 31) << 2;
      int ge = e0 + be + c4;
      if (ge > E - 4) ge = E - 4;  // clamp; garbage rows are guarded at write
      *(float4*)&a_lds[k][c4] = *(const float4*)&uT[(size_t)(k0 + k) * E + ge];
      *(float4*)&b_lds[k][c4] = *(const float4*)&w2[(size_t)(k0 + k) * 4096 + bc + c4];
    }
    __syncthreads();
    #pragma unroll
    for (int k = 0; k < 64; ++k) {
      float a[8], b[8];
      *(float4*)&a[0] = *(const float4*)&a_lds[k][ty * 8];
      *(float4*)&a[4] = *(const float4*)&a_lds[k][ty * 8 + 4];
      *(float4*)&b[0] = *(const float4*)&b_lds[k][tx * 8];
      *(float4*)&b[4] = *(const float4*)&b_lds[k][tx * 8 + 4];
      #pragma unroll
      for (int i = 0; i < 8; ++i)
        #pragma unroll
        for (int j = 0; j < 8; ++j) acc[i][j] += a[i] * b[j];
    }
    __syncthreads();
  }
  float bias[8];
  *(float4*)&bias[0] = *(const float4*)&b2[bc + tx * 8];
  *(float4*)&bias[4] = *(const float4*)&b2[bc + tx * 8 + 4];
  #pragma unroll
  for (int i = 0; i < 8; ++i) {
    int le = be + ty * 8 + i;
    if (le >= ce) break;
    float4 v0, v1;
    v0.x = acc[i][0] + bias[0]; v0.y = acc[i][1] + bias[1];
    v0.z = acc[i][2] + bias[2]; v0.w = acc[i][3] + bias[3];
    v1.x = acc[i][4] + bias[4]; v1.y = acc[i][5] + bias[5];
    v1.z = acc[i][6] + bias[6]; v1.w = acc[i][7] + bias[7];
    size_t base = (size_t)le * 4096 + bc + tx * 8;
    *(float4*)&W[base] = v0;
    *(float4*)&W[base + 4] = v1;
  }
}

// ------- einsum msg = s @ W_e, scaled scatter-add to agg[dst] -------
__global__ __launch_bounds__(256) void einsum_scatter_k(const float* __restrict__ W,
    const float* __restrict__ out, const int* __restrict__ src, const int* __restrict__ dst,
    const float* __restrict__ inv_deg, float* __restrict__ agg, int e0, int ce) {
  __shared__ float s_lds[4][H];
  int t = threadIdx.x;
  int wv = t >> 6, o = t & 63;
  int le = blockIdx.x * 4 + wv;
  bool valid = le < ce;
  int e = e0 + (valid ? le : 0);
  int sn = src[e];
  s_lds[wv][o] = out[(size_t)sn * H + o];
  __syncthreads();
  if (!valid) return;
  const float* We = W + (size_t)le * 4096;
  float acc = 0.f;
  #pragma unroll 8
  for (int i = 0; i < H; ++i) acc += s_lds[wv][i] * We[i * H + o];
  int dn = dst[e];
  atomicAdd(&agg[(size_t)dn * H + o], acc * inv_deg[dn]);
}

// ------- m = relu(agg + out @ conv_root + bias) -------
__global__ __launch_bounds__(256) void conv_m_k(const float* __restrict__ agg,
    const float* __restrict__ out, const float* __restrict__ root,
    const float* __restrict__ bias, float* __restrict__ m, int n) {
  __shared__ float o_lds[4][H];
  int t = threadIdx.x;
  int wv = t >> 6, c = t & 63;
  int node = blockIdx.x * 4 + wv;
  int nodec = node < n ? node : n - 1;
  o_lds[wv][c] = out[(size_t)nodec * H + c];
  __syncthreads();
  if (node >= n) return;
  float acc = agg[(size_t)node * H + c] + bias[c];
  #pragma unroll
  for (int j = 0; j < H; ++j) acc += o_lds[wv][j] * root[j * H + c];
  m[(size_t)node * H + c] = fmaxf(acc, 0.f);
}

// ------- GRU: 16 nodes/block, 192 threads (one per gate column) -------
__global__ __launch_bounds__(192) void gru_k(const float* __restrict__ m,
    const float* __restrict__ h, const float* __restrict__ wih, const float* __restrict__ whh,
    const float* __restrict__ bih, const float* __restrict__ bhh,
    float* __restrict__ hnew, int n) {
  __shared__ float m_lds[16][H], h_lds[16][H];
  __shared__ float gib[16][192], ghb[16][192];
  int t = threadIdx.x;
  int n0 = blockIdx.x * 16;
  for (int p = 0; p < 6; ++p) {
    int idx = p * 192 + t;
    if (idx < 16 * H) {
      int q = idx >> 6, c = idx & 63;
      int nn = n0 + q;
      float mv = 0.f, hv = 0.f;
      if (nn < n) { mv = m[(size_t)nn * H + c]; hv = h[(size_t)nn * H + c]; }
      m_lds[q][c] = mv;
      h_lds[q][c] = hv;
    }
  }
  __syncthreads();
  float gi[16], gh[16];
  float bi = bih[t], bh = bhh[t];
  #pragma unroll
  for (int q = 0; q < 16; ++q) { gi[q] = bi; gh[q] = bh; }
  for (int j = 0; j < H; ++j) {
    float wi = wih[j * 192 + t];
    float wh = whh[j * 192 + t];
    #pragma unroll
    for (int q = 0; q < 16; ++q) {
      gi[q] += m_lds[q][j] * wi;
      gh[q] += h_lds[q][j] * wh;
    }
  }
  #pragma unroll
  for (int q = 0; q < 16; ++q) { gib[q][t] = gi[q]; ghb[q][t] = gh[q]; }
  __syncthreads();
  for (int p = 0; p < 6; ++p) {
    int idx = p * 192 + t;
    if (idx < 16 * H) {
      int q = idx >> 6, c = idx & 63;
      int nn = n0 + q;
      if (nn < n) {
        float r = sigmoidf_(gib[q][c] + ghb[q][c]);
        float z = sigmoidf_(gib[q][64 + c] + ghb[q][64 + c]);
        float ng = tanhf(gib[q][128 + c] + r * ghb[q][128 + c]);
        hnew[(size_t)nn * H + c] = (1.f - z) * ng + z * h_lds[q][c];
      }
    }
  }
}

// ------- graph ranges from sorted batch -------
__global__ void graph_ranges_k(const int* __restrict__ batch, int* __restrict__ gs,
                               int* __restrict__ ge, int n) {
  int i = blockIdx.x * 256 + threadIdx.x;
  if (i >= n) return;
  int b = batch[i];
  atomicMin(&gs[b], i);
  atomicMax(&ge[b], i + 1);
}

// ------- LSTM cell: one block per graph -------
__global__ __launch_bounds__(256) void lstm_k(const float* __restrict__ qstar,
    float* __restrict__ hs, float* __restrict__ cs,
    const float* __restrict__ wih, const float* __restrict__ whh,
    const float* __restrict__ bih, const float* __restrict__ bhh) {
  int b = blockIdx.x;
  int g = threadIdx.x;  // 0..255
  __shared__ float q[2 * H], hh[H], gate[256];
  if (g < 2 * H) q[g] = qstar[b * 2 * H + g];
  if (g >= 128 && g < 192) hh[g - 128] = hs[b * H + (g - 128)];
  __syncthreads();
  float acc = bih[g] + bhh[g];
  #pragma unroll 4
  for (int j = 0; j < 2 * H; ++j) acc += q[j] * wih[j * 256 + g];
  #pragma unroll 4
  for (int j = 0; j < H; ++j) acc += hh[j] * whh[j * 256 + g];
  gate[g] = acc;
  __syncthreads();
  if (g < H) {
    float ig = sigmoidf_(gate[g]);
    float fg = sigmoidf_(gate[64 + g]);
    float gg = tanhf(gate[128 + g]);
    float og = sigmoidf_(gate[192 + g]);
    float c2 = fg * cs[b * H + g] + ig * gg;
    float h2 = og * tanhf(c2);
    cs[b * H + g] = c2;
    hs[b * H + g] = h2;
  }
}

// ------- Set2Set attention: one block per graph (batch is sorted) -------
__global__ __launch_bounds__(256) void attn_k(const float* __restrict__ out,
    const float* __restrict__ hs, const int* __restrict__ gstart, const int* __restrict__ gend,
    float* __restrict__ en, float* __restrict__ qstar) {
  int b = blockIdx.x;
  int t = threadIdx.x;
  __shared__ float q[H];
  __shared__ float red[256];
  int s = gstart[b], epos = gend[b];
  if (s > epos) { s = 0; epos = 0; }  // empty graph
  if (t < H) q[t] = hs[b * H + t];
  __syncthreads();
  // phase A: en + max
  float lmax = -INFINITY;
  for (int nn = s + t; nn < epos; nn += 256) {
    float d = 0.f;
    const float* orow = &out[(size_t)nn * H];
    #pragma unroll
    for (int j = 0; j < H; ++j) d += orow[j] * q[j];
    en[nn] = d;
    lmax = fmaxf(lmax, d);
  }
  red[t] = lmax;
  __syncthreads();
  for (int st = 128; st > 0; st >>= 1) {
    if (t < st) red[t] = fmaxf(red[t], red[t + st]);
    __syncthreads();
  }
  float mx = red[0];
  __syncthreads();
  // phase B: exp + sum
  float lsum = 0.f;
  for (int nn = s + t; nn < epos; nn += 256) {
    float e_ = expf(en[nn] - mx);
    en[nn] = e_;
    lsum += e_;
  }
  red[t] = lsum;
  __syncthreads();
  for (int st = 128; st > 0; st >>= 1) {
    if (t < st) red[t] += red[t + st];
    __syncthreads();
  }
  float inv = 1.f / (red[0] + 1e-16f);
  __syncthreads();
  // phase C: r = sum a_n * out[n]
  int hch = t & 63, sub = t >> 6;  // 4 subgroups of 64
  float racc = 0.f;
  for (int nn = s + sub; nn < epos; nn += 4) {
    racc += en[nn] * out[(size_t)nn * H + hch];
  }
  red[t] = racc;
  __syncthreads();
  if (t < H) {
    float r = (red[t] + red[64 + t] + red[128 + t] + red[192 + t]) * inv;
    qstar[b * 2 * H + H + t] = r;
    qstar[b * 2 * H + t] = q[t];
  }
}

// ------- final: relu(qstar @ lin1) @ lin2 + b -------
__global__ __launch_bounds__(64) void final_k(const float* __restrict__ qstar,
    const float* __restrict__ w1, const float* __restrict__ b1,
    const float* __restrict__ w2, const float* __restrict__ b2,
    float* __restrict__ outp) {
  int b = blockIdx.x, t = threadIdx.x;
  __shared__ float q[2 * H];
  q[t] = qstar[b * 2 * H + t];
  q[64 + t] = qstar[b * 2 * H + 64 + t];
  __syncthreads();
  float acc = b1[t];
  #pragma unroll 4
  for (int j = 0; j < 2 * H; ++j) acc += q[j] * w1[j * H + t];
  acc = fmaxf(acc, 0.f);
  float v = acc * w2[t];
  #pragma unroll
  for (int off = 32; off > 0; off >>= 1) v += __shfl_down(v, off, 64);
  if (t == 0) outp[b] = v + b2[0];
}

extern "C" void kernel_launch(void* const* d_in, const int* in_sizes, int n_in,
                              void* d_out, int out_size, void* d_ws, size_t ws_size,
                              hipStream_t stream) {
  const float* x         = (const float*)d_in[0];
  const int*   edge_idx  = (const int*)d_in[1];
  const int*   batch     = (const int*)d_in[2];
  const float* edge_attr = (const float*)d_in[3];
  const float* lin0_w = (const float*)d_in[4];
  const float* lin0_b = (const float*)d_in[5];
  const float* nn_w1  = (const float*)d_in[6];
  const float* nn_b1  = (const float*)d_in[7];
  const float* nn_w2  = (const float*)d_in[8];
  const float* nn_b2  = (const float*)d_in[9];
  const float* conv_root = (const float*)d_in[10];
  const float* conv_bias = (const float*)d_in[11];
  const float* gru_wih = (const float*)d_in[12];
  const float* gru_whh = (const float*)d_in[13];
  const float* gru_bih = (const float*)d_in[14];
  const float* gru_bhh = (const float*)d_in[15];
  const float* lstm_wih = (const float*)d_in[16];
  const float* lstm_whh = (const float*)d_in[17];
  const float* lstm_bih = (const float*)d_in[18];
  const float* lstm_bhh = (const float*)d_in[19];
  const float* lin1_w = (const float*)d_in[20];
  const float* lin1_b = (const float*)d_in[21];
  const float* lin2_w = (const float*)d_in[22];
  const float* lin2_b = (const float*)d_in[23];

  int N = in_sizes[2];
  int E = in_sizes[1] / 2;
  int B = out_size;
  const int* src = edge_idx;
  const int* dst = edge_idx + E;

  char* p = (char*)d_ws;
  auto carve = [&](size_t bytes) -> void* {
    void* r = (void*)p;
    p += (bytes + 255) & ~(size_t)255;
    return r;
  };
  float* bufA   = (float*)carve((size_t)N * H * 4);
  float* bufB   = (float*)carve((size_t)N * H * 4);
  float* uT     = (float*)carve((size_t)NNHID * E * 4);
  float* agg    = (float*)carve((size_t)N * H * 4);
  float* mbuf   = (float*)carve((size_t)N * H * 4);
  float* invdeg = (float*)carve((size_t)N * 4);
  float* enbuf  = (float*)carve((size_t)N * 4);
  float* qstar  = (float*)carve((size_t)B * 2 * H * 4);
  float* hsbuf  = (float*)carve((size_t)B * H * 4);
  float* csbuf  = (float*)carve((size_t)B * H * 4);
  int*   gstart = (int*)carve((size_t)B * 4);
  int*   gend   = (int*)carve((size_t)B * 4);
  size_t used = (size_t)(p - (char*)d_ws);
  size_t avail = ws_size > used ? ws_size - used : 0;
  float* Wbuf = (float*)p;
  size_t maxe = avail / ((size_t)4096 * 4);
  int chunk;
  bool fullW;
  if (maxe >= (size_t)E) { chunk = E; fullW = true; }
  else {
    chunk = (int)(maxe & ~(size_t)127);
    if (chunk < 128) chunk = 128;
    fullW = false;
  }

  dim3 b256(256);
  // degree -> inv
  fill_u32_k<<<dim3(64), b256, 0, stream>>>((uint32_t*)invdeg, 0u, N);
  count_deg_k<<<dim3((E + 255) / 256), b256, 0, stream>>>(dst, invdeg, E);
  inv_deg_k<<<dim3((N + 255) / 256), b256, 0, stream>>>(invdeg, N);
  // lin0 -> bufA (out = h)
  lin0_k<<<dim3((N + 3) / 4), b256, 0, stream>>>(x, lin0_w, lin0_b, bufA, N);
  // edge MLP layer 1 -> uT
  edge_mlp1_k<<<dim3((E + 63) / 64), dim3(128), 0, stream>>>(edge_attr, nn_w1, nn_b1, uT, E);
  if (fullW) {
    gemm_w_k<<<dim3((E + 127) / 128, 32), b256, 0, stream>>>(uT, nn_w2, nn_b2, Wbuf, E, 0, E);
  }
  float* cur = bufA;
  float* nxt = bufB;
  for (int it = 0; it < 3; ++it) {
    fill_u32_k<<<dim3(1024), b256, 0, stream>>>((uint32_t*)agg, 0u, (long long)N * H);
    if (fullW) {
      einsum_scatter_k<<<dim3((E + 3) / 4), b256, 0, stream>>>(Wbuf, cur, src, dst, invdeg, agg, 0, E);
    } else {
      for (int e0 = 0; e0 < E; e0 += chunk) {
        int ce = (E - e0 < chunk) ? (E - e0) : chunk;
        gemm_w_k<<<dim3((ce + 127) / 128, 32), b256, 0, stream>>>(uT, nn_w2, nn_b2, Wbuf, E, e0, ce);
        einsum_scatter_k<<<dim3((ce + 3) / 4), b256, 0, stream>>>(Wbuf, cur, src, dst, invdeg, agg, e0, ce);
      }
    }
    conv_m_k<<<dim3((N + 3) / 4), b256, 0, stream>>>(agg, cur, conv_root, conv_bias, mbuf, N);
    gru_k<<<dim3((N + 15) / 16), dim3(192), 0, stream>>>(mbuf, cur, gru_wih, gru_whh, gru_bih, gru_bhh, nxt, N);
    float* tmp = cur; cur = nxt; nxt = tmp;
  }
  // Set2Set
  fill_u32_k<<<dim3(16), b256, 0, stream>>>((uint32_t*)qstar, 0u, (long long)B * 2 * H);
  fill_u32_k<<<dim3(4), b256, 0, stream>>>((uint32_t*)hsbuf, 0u, (long long)B * H);
  fill_u32_k<<<dim3(4), b256, 0, stream>>>((uint32_t*)csbuf, 0u, (long long)B * H);
  fill_u32_k<<<dim3(1), b256, 0, stream>>>((uint32_t*)gstart, (uint32_t)N, B);
  fill_u32_k<<<dim3(1), b256, 0, stream>>>((uint32_t*)gend, 0u, B);
  graph_ranges_k<<<dim3((N + 255) / 256), b256, 0, stream>>>(batch, gstart, gend, N);
  for (int s = 0; s < 3; ++s) {
    lstm_k<<<dim3(B), b256, 0, stream>>>(qstar, hsbuf, csbuf, lstm_wih, lstm_whh, lstm_bih, lstm_bhh);
    attn_k<<<dim3(B), b256, 0, stream>>>(cur, hsbuf, gstart, gend, enbuf, qstar);
  }
  final_k<<<dim3(B), dim3(64), 0, stream>>>(qstar, lin1_w, lin1_b, lin2_w, lin2_b, (float*)d_out);
}

// Round 2
// 1239.534 us; speedup vs baseline: 3.9721x; 3.9721x over previous
//
#include <hip/hip_runtime.h>
#include <cstdint>
#include <cmath>

#define H 64
#define NFEAT 32
#define NNHID 128
#define TE_WG 128
#define TE_WAVE 32

typedef __attribute__((ext_vector_type(8))) short bf16x8;
typedef __attribute__((ext_vector_type(4))) float f32x4;

static __device__ __forceinline__ float sigmoidf_(float x) { return 1.f / (1.f + expf(-x)); }

static __device__ __forceinline__ unsigned bf16_rne_bits(float v) {
  unsigned u = __float_as_uint(v);
  return (u + 0x7fffu + ((u >> 16) & 1u)) >> 16;
}

// ---------------- generic fill ----------------
__global__ void fill_u32_k(uint32_t* __restrict__ p, uint32_t v, long long n) {
  long long i = (long long)blockIdx.x * blockDim.x + threadIdx.x;
  long long stride = (long long)gridDim.x * blockDim.x;
  for (; i < n; i += stride) p[i] = v;
}

// ---------------- degree ----------------
__global__ void count_deg_k(const int* __restrict__ dst, float* __restrict__ deg, int E) {
  int i = blockIdx.x * 256 + threadIdx.x;
  if (i < E) atomicAdd(&deg[dst[i]], 1.f);
}
__global__ void inv_deg_k(float* __restrict__ deg, int n) {
  int i = blockIdx.x * 256 + threadIdx.x;
  if (i < n) deg[i] = 1.f / fmaxf(deg[i], 1.f);
}

// ---------------- lin0 ----------------
__global__ __launch_bounds__(256) void lin0_k(const float* __restrict__ x,
    const float* __restrict__ w, const float* __restrict__ b,
    float* __restrict__ out, int n) {
  __shared__ float xr[4][NFEAT];
  int t = threadIdx.x;
  int nodeblk = blockIdx.x * 4;
  if (t < 4 * NFEAT) {
    int nn = nodeblk + t / NFEAT;
    xr[t / NFEAT][t % NFEAT] = (nn < n) ? x[(size_t)nn * NFEAT + (t % NFEAT)] : 0.f;
  }
  __syncthreads();
  int node = nodeblk + t / H;
  int c = t % H;
  if (node >= n) return;
  float acc = b[c];
  #pragma unroll
  for (int j = 0; j < NFEAT; ++j) acc += xr[t / H][j] * w[j * H + c];
  out[(size_t)node * H + c] = fmaxf(acc, 0.f);
}

// ------------- edge MLP layer1 -> u row-major [E][128] -------------
__global__ __launch_bounds__(128) void edge_mlp1_k(const float* __restrict__ ea,
    const float* __restrict__ w1, const float* __restrict__ b1,
    float* __restrict__ u, int E) {
  __shared__ float ar[64][H];        // [edge][j]
  __shared__ float ut[NNHID][65];    // [k][e] padded
  int t = threadIdx.x;
  int e0 = blockIdx.x * 64;
  #pragma unroll
  for (int p = 0; p < 32; ++p) {
    int idx = p * 128 + t;
    int e = idx >> 6, j = idx & 63;
    ar[e][j] = (e0 + e < E) ? ea[(size_t)(e0 + e) * H + j] : 0.f;
  }
  __syncthreads();
  float bb = b1[t];
  for (int et = 0; et < 64; et += 16) {
    float acc[16];
    #pragma unroll
    for (int q = 0; q < 16; ++q) acc[q] = bb;
    #pragma unroll
    for (int j = 0; j < H; ++j) {
      float wv = w1[j * NNHID + t];
      #pragma unroll
      for (int q = 0; q < 16; ++q) acc[q] += ar[et + q][j] * wv;
    }
    #pragma unroll
    for (int q = 0; q < 16; ++q) ut[t][et + q] = fmaxf(acc[q], 0.f);
  }
  __syncthreads();
  for (int e = 0; e < 64; ++e) {
    if (e0 + e < E) u[(size_t)(e0 + e) * NNHID + t] = ut[t][e];
  }
}

// ------- pack u[E][128] fp32 -> split-bf16 A fragments -------
// frag f = (e/16)*4 + kt ; element: lane l, b: A[e0+(l&15)][kt*32 + (l>>4)*8 + b]
__global__ __launch_bounds__(256) void pack_u_k(const float* __restrict__ u,
    short* __restrict__ hi, short* __restrict__ lo, int E, int nfrag) {
  int g = blockIdx.x * 256 + threadIdx.x;
  int lane = g & 63, frag = g >> 6;
  if (frag >= nfrag) return;
  int et = frag >> 2, kt = frag & 3;
  int e = et * 16 + (lane & 15);
  int k0 = kt * 32 + (lane >> 4) * 8;
  bf16x8 hv, lv;
  if (e < E) {
    #pragma unroll
    for (int b = 0; b < 8; ++b) {
      float v = u[(size_t)e * NNHID + k0 + b];
      unsigned hb = bf16_rne_bits(v);
      float hf = __uint_as_float(hb << 16);
      unsigned lb = bf16_rne_bits(v - hf);
      hv[b] = (short)hb;
      lv[b] = (short)lb;
    }
  } else {
    #pragma unroll
    for (int b = 0; b < 8; ++b) { hv[b] = 0; lv[b] = 0; }
  }
  size_t off = (size_t)frag * 512 + lane * 8;
  *(bf16x8*)(hi + off) = hv;
  *(bf16x8*)(lo + off) = lv;
}

// ------- pack w2[128][4096] fp32 -> split-bf16 B fragments -------
// frag f = (n/16)*4 + kt ; element: lane l, b: w2[kt*32+(l>>4)*8+b][n0+(l&15)]
__global__ __launch_bounds__(256) void pack_w2_k(const float* __restrict__ w2,
    short* __restrict__ hi, short* __restrict__ lo) {
  int g = blockIdx.x * 256 + threadIdx.x;
  int lane = g & 63, frag = g >> 6;
  if (frag >= 1024) return;
  int ntile = frag >> 2, kt = frag & 3;
  int n = ntile * 16 + (lane & 15);
  int k0 = kt * 32 + (lane >> 4) * 8;
  bf16x8 hv, lv;
  #pragma unroll
  for (int b = 0; b < 8; ++b) {
    float v = w2[(size_t)(k0 + b) * 4096 + n];
    unsigned hb = bf16_rne_bits(v);
    float hf = __uint_as_float(hb << 16);
    unsigned lb = bf16_rne_bits(v - hf);
    hv[b] = (short)hb;
    lv[b] = (short)lb;
  }
  size_t off = (size_t)frag * 512 + lane * 8;
  *(bf16x8*)(hi + off) = hv;
  *(bf16x8*)(lo + off) = lv;
}

// ------- fused W-GEMM (split-bf16 MFMA) + einsum + scatter-mean -------
// Per wg: 128 edges; wave w owns 32 edges (2 subtiles of 16).
// msg[e][o] = sum_i s[e][i] * ( (u@w2)[e][i*64+o] + b2[i*64+o] )
__global__ __launch_bounds__(256) void fused_msg_k(
    const short* __restrict__ upk_hi, const short* __restrict__ upk_lo,
    const short* __restrict__ wpk_hi, const short* __restrict__ wpk_lo,
    const float* __restrict__ out, const int* __restrict__ src,
    const int* __restrict__ dst, const float* __restrict__ inv_deg,
    const float* __restrict__ b2, float* __restrict__ agg, int E) {
  __shared__ float s_lds[TE_WG][H + 1];
  __shared__ float b2_lds[4096];
  int t = threadIdx.x;
  int e0 = blockIdx.x * TE_WG;
  // stage s = out[src[e]]
  for (int rr = 0; rr < TE_WG / 4; ++rr) {
    int row = (t >> 6) + rr * 4;
    int e = e0 + row;
    int ee = e < E ? e : E - 1;
    int sn = src[ee];
    s_lds[row][t & 63] = out[(size_t)sn * H + (t & 63)];
  }
  for (int rr = 0; rr < 16; ++rr) b2_lds[rr * 256 + t] = b2[rr * 256 + t];
  __syncthreads();

  int wave = t >> 6, lane = t & 63;
  int ebase = e0 + wave * TE_WAVE;
  int lhi = lane >> 4;      // 0..3
  int lrow4 = lhi * 4;      // C row group base
  int lcol = lane & 15;

  // A fragments: 2 subtiles x 4 ktiles, hi+lo
  bf16x8 a_hi[2][4], a_lo[2][4];
  size_t abase = ((size_t)(ebase >> 4) * 4) * 512 + lane * 8;
  #pragma unroll
  for (int ms = 0; ms < 2; ++ms)
    #pragma unroll
    for (int kt = 0; kt < 4; ++kt) {
      size_t off = abase + (size_t)(ms * 4 + kt) * 512;
      a_hi[ms][kt] = *(const bf16x8*)(upk_hi + off);
      a_lo[ms][kt] = *(const bf16x8*)(upk_lo + off);
    }

  f32x4 msg[2][4];
  #pragma unroll
  for (int ms = 0; ms < 2; ++ms)
    #pragma unroll
    for (int oc = 0; oc < 4; ++oc) msg[ms][oc] = (f32x4){0.f, 0.f, 0.f, 0.f};

  int srow = wave * TE_WAVE;
  const short* wh = wpk_hi + lane * 8;
  const short* wl = wpk_lo + lane * 8;

  for (int i = 0; i < H; ++i) {
    float sv[2][4];
    #pragma unroll
    for (int ms = 0; ms < 2; ++ms)
      #pragma unroll
      for (int r = 0; r < 4; ++r)
        sv[ms][r] = s_lds[srow + ms * 16 + lrow4 + r][i];
    #pragma unroll
    for (int oc = 0; oc < 4; ++oc) {
      int ntile = i * 4 + oc;
      float b2v = b2_lds[i * 64 + oc * 16 + lcol];
      bf16x8 bh[4], bl[4];
      #pragma unroll
      for (int kt = 0; kt < 4; ++kt) {
        size_t off = (size_t)(ntile * 4 + kt) * 512;
        bh[kt] = *(const bf16x8*)(wh + off);
        bl[kt] = *(const bf16x8*)(wl + off);
      }
      #pragma unroll
      for (int ms = 0; ms < 2; ++ms) {
        f32x4 acc = (f32x4){0.f, 0.f, 0.f, 0.f};
        #pragma unroll
        for (int kt = 0; kt < 4; ++kt) {
          acc = __builtin_amdgcn_mfma_f32_16x16x32_bf16(a_hi[ms][kt], bh[kt], acc, 0, 0, 0);
          acc = __builtin_amdgcn_mfma_f32_16x16x32_bf16(a_hi[ms][kt], bl[kt], acc, 0, 0, 0);
          acc = __builtin_amdgcn_mfma_f32_16x16x32_bf16(a_lo[ms][kt], bh[kt], acc, 0, 0, 0);
        }
        #pragma unroll
        for (int r = 0; r < 4; ++r)
          msg[ms][oc][r] += sv[ms][r] * (acc[r] + b2v);
      }
    }
  }

  // scatter-mean writeback
  #pragma unroll
  for (int ms = 0; ms < 2; ++ms) {
    #pragma unroll
    for (int r = 0; r < 4; ++r) {
      int e = ebase + ms * 16 + lrow4 + r;
      if (e < E) {
        int dn = dst[e];
        float idg = inv_deg[dn];
        #pragma unroll
        for (int oc = 0; oc < 4; ++oc) {
          atomicAdd(&agg[(size_t)dn * H + oc * 16 + lcol], msg[ms][oc][r] * idg);
        }
      }
    }
  }
}

// ------- m = relu(agg + out @ conv_root + bias) -------
__global__ __launch_bounds__(256) void conv_m_k(const float* __restrict__ agg,
    const float* __restrict__ out, const float* __restrict__ root,
    const float* __restrict__ bias, float* __restrict__ m, int n) {
  __shared__ float o_lds[4][H];
  int t = threadIdx.x;
  int wv = t >> 6, c = t & 63;
  int node = blockIdx.x * 4 + wv;
  int nodec = node < n ? node : n - 1;
  o_lds[wv][c] = out[(size_t)nodec * H + c];
  __syncthreads();
  if (node >= n) return;
  float acc = agg[(size_t)node * H + c] + bias[c];
  #pragma unroll
  for (int j = 0; j < H; ++j) acc += o_lds[wv][j] * root[j * H + c];
  m[(size_t)node * H + c] = fmaxf(acc, 0.f);
}

// ------- GRU -------
__global__ __launch_bounds__(192) void gru_k(const float* __restrict__ m,
    const float* __restrict__ h, const float* __restrict__ wih, const float* __restrict__ whh,
    const float* __restrict__ bih, const float* __restrict__ bhh,
    float* __restrict__ hnew, int n) {
  __shared__ float m_lds[16][H], h_lds[16][H];
  __shared__ float gib[16][192], ghb[16][192];
  int t = threadIdx.x;
  int n0 = blockIdx.x * 16;
  for (int p = 0; p < 6; ++p) {
    int idx = p * 192 + t;
    if (idx < 16 * H) {
      int q = idx >> 6, c = idx & 63;
      int nn = n0 + q;
      float mv = 0.f, hv = 0.f;
      if (nn < n) { mv = m[(size_t)nn * H + c]; hv = h[(size_t)nn * H + c]; }
      m_lds[q][c] = mv;
      h_lds[q][c] = hv;
    }
  }
  __syncthreads();
  float gi[16], gh[16];
  float bi = bih[t], bh = bhh[t];
  #pragma unroll
  for (int q = 0; q < 16; ++q) { gi[q] = bi; gh[q] = bh; }
  for (int j = 0; j < H; ++j) {
    float wi = wih[j * 192 + t];
    float wh = whh[j * 192 + t];
    #pragma unroll
    for (int q = 0; q < 16; ++q) {
      gi[q] += m_lds[q][j] * wi;
      gh[q] += h_lds[q][j] * wh;
    }
  }
  #pragma unroll
  for (int q = 0; q < 16; ++q) { gib[q][t] = gi[q]; ghb[q][t] = gh[q]; }
  __syncthreads();
  for (int p = 0; p < 6; ++p) {
    int idx = p * 192 + t;
    if (idx < 16 * H) {
      int q = idx >> 6, c = idx & 63;
      int nn = n0 + q;
      if (nn < n) {
        float r = sigmoidf_(gib[q][c] + ghb[q][c]);
        float z = sigmoidf_(gib[q][64 + c] + ghb[q][64 + c]);
        float ng = tanhf(gib[q][128 + c] + r * ghb[q][128 + c]);
        hnew[(size_t)nn * H + c] = (1.f - z) * ng + z * h_lds[q][c];
      }
    }
  }
}

// ------- graph ranges -------
__global__ void graph_ranges_k(const int* __restrict__ batch, int* __restrict__ gs,
                               int* __restrict__ ge, int n) {
  int i = blockIdx.x * 256 + threadIdx.x;
  if (i >= n) return;
  int b = batch[i];
  atomicMin(&gs[b], i);
  atomicMax(&ge[b], i + 1);
}

// ------- LSTM -------
__global__ __launch_bounds__(256) void lstm_k(const float* __restrict__ qstar,
    float* __restrict__ hs, float* __restrict__ cs,
    const float* __restrict__ wih, const float* __restrict__ whh,
    const float* __restrict__ bih, const float* __restrict__ bhh) {
  int b = blockIdx.x;
  int g = threadIdx.x;
  __shared__ float q[2 * H], hh[H], gate[256];
  if (g < 2 * H) q[g] = qstar[b * 2 * H + g];
  if (g >= 128 && g < 192) hh[g - 128] = hs[b * H + (g - 128)];
  __syncthreads();
  float acc = bih[g] + bhh[g];
  #pragma unroll 4
  for (int j = 0; j < 2 * H; ++j) acc += q[j] * wih[j * 256 + g];
  #pragma unroll 4
  for (int j = 0; j < H; ++j) acc += hh[j] * whh[j * 256 + g];
  gate[g] = acc;
  __syncthreads();
  if (g < H) {
    float ig = sigmoidf_(gate[g]);
    float fg = sigmoidf_(gate[64 + g]);
    float gg = tanhf(gate[128 + g]);
    float og = sigmoidf_(gate[192 + g]);
    float c2 = fg * cs[b * H + g] + ig * gg;
    float h2 = og * tanhf(c2);
    cs[b * H + g] = c2;
    hs[b * H + g] = h2;
  }
}

// ------- Set2Set attention -------
__global__ __launch_bounds__(256) void attn_k(const float* __restrict__ out,
    const float* __restrict__ hs, const int* __restrict__ gstart, const int* __restrict__ gend,
    float* __restrict__ en, float* __restrict__ qstar) {
  int b = blockIdx.x;
  int t = threadIdx.x;
  __shared__ float q[H];
  __shared__ float red[256];
  int s = gstart[b], epos = gend[b];
  if (s > epos) { s = 0; epos = 0; }
  if (t < H) q[t] = hs[b * H + t];
  __syncthreads();
  float lmax = -INFINITY;
  for (int nn = s + t; nn < epos; nn += 256) {
    float d = 0.f;
    const float* orow = &out[(size_t)nn * H];
    #pragma unroll
    for (int j = 0; j < H; ++j) d += orow[j] * q[j];
    en[nn] = d;
    lmax = fmaxf(lmax, d);
  }
  red[t] = lmax;
  __syncthreads();
  for (int st = 128; st > 0; st >>= 1) {
    if (t < st) red[t] = fmaxf(red[t], red[t + st]);
    __syncthreads();
  }
  float mx = red[0];
  __syncthreads();
  float lsum = 0.f;
  for (int nn = s + t; nn < epos; nn += 256) {
    float e_ = expf(en[nn] - mx);
    en[nn] = e_;
    lsum += e_;
  }
  red[t] = lsum;
  __syncthreads();
  for (int st = 128; st > 0; st >>= 1) {
    if (t < st) red[t] += red[t + st];
    __syncthreads();
  }
  float inv = 1.f / (red[0] + 1e-16f);
  __syncthreads();
  int hch = t & 63, sub = t >> 6;
  float racc = 0.f;
  for (int nn = s + sub; nn < epos; nn += 4) {
    racc += en[nn] * out[(size_t)nn * H + hch];
  }
  red[t] = racc;
  __syncthreads();
  if (t < H) {
    float r = (red[t] + red[64 + t] + red[128 + t] + red[192 + t]) * inv;
    qstar[b * 2 * H + H + t] = r;
    qstar[b * 2 * H + t] = q[t];
  }
}

// ------- final -------
__global__ __launch_bounds__(64) void final_k(const float* __restrict__ qstar,
    const float* __restrict__ w1, const float* __restrict__ b1,
    const float* __restrict__ w2, const float* __restrict__ b2,
    float* __restrict__ outp) {
  int b = blockIdx.x, t = threadIdx.x;
  __shared__ float q[2 * H];
  q[t] = qstar[b * 2 * H + t];
  q[64 + t] = qstar[b * 2 * H + 64 + t];
  __syncthreads();
  float acc = b1[t];
  #pragma unroll 4
  for (int j = 0; j < 2 * H; ++j) acc += q[j] * w1[j * H + t];
  acc = fmaxf(acc, 0.f);
  float v = acc * w2[t];
  #pragma unroll
  for (int off = 32; off > 0; off >>= 1) v += __shfl_down(v, off, 64);
  if (t == 0) outp[b] = v + b2[0];
}

extern "C" void kernel_launch(void* const* d_in, const int* in_sizes, int n_in,
                              void* d_out, int out_size, void* d_ws, size_t ws_size,
                              hipStream_t stream) {
  const float* x         = (const float*)d_in[0];
  const int*   edge_idx  = (const int*)d_in[1];
  const int*   batch     = (const int*)d_in[2];
  const float* edge_attr = (const float*)d_in[3];
  const float* lin0_w = (const float*)d_in[4];
  const float* lin0_b = (const float*)d_in[5];
  const float* nn_w1  = (const float*)d_in[6];
  const float* nn_b1  = (const float*)d_in[7];
  const float* nn_w2  = (const float*)d_in[8];
  const float* nn_b2  = (const float*)d_in[9];
  const float* conv_root = (const float*)d_in[10];
  const float* conv_bias = (const float*)d_in[11];
  const float* gru_wih = (const float*)d_in[12];
  const float* gru_whh = (const float*)d_in[13];
  const float* gru_bih = (const float*)d_in[14];
  const float* gru_bhh = (const float*)d_in[15];
  const float* lstm_wih = (const float*)d_in[16];
  const float* lstm_whh = (const float*)d_in[17];
  const float* lstm_bih = (const float*)d_in[18];
  const float* lstm_bhh = (const float*)d_in[19];
  const float* lin1_w = (const float*)d_in[20];
  const float* lin1_b = (const float*)d_in[21];
  const float* lin2_w = (const float*)d_in[22];
  const float* lin2_b = (const float*)d_in[23];

  int N = in_sizes[2];
  int E = in_sizes[1] / 2;
  int B = out_size;
  const int* src = edge_idx;
  const int* dst = edge_idx + E;

  char* p = (char*)d_ws;
  auto carve = [&](size_t bytes) -> void* {
    void* r = (void*)p;
    p += (bytes + 255) & ~(size_t)255;
    return r;
  };
  int etiles = (E + 15) / 16;
  int nfrag_u = etiles * 4;
  float* bufA   = (float*)carve((size_t)N * H * 4);
  float* bufB   = (float*)carve((size_t)N * H * 4);
  float* u_rm   = (float*)carve((size_t)E * NNHID * 4);
  short* upk_hi = (short*)carve((size_t)nfrag_u * 512 * 2);
  short* upk_lo = (short*)carve((size_t)nfrag_u * 512 * 2);
  short* wpk_hi = (short*)carve((size_t)1024 * 512 * 2);
  short* wpk_lo = (short*)carve((size_t)1024 * 512 * 2);
  float* agg    = (float*)carve((size_t)N * H * 4);
  float* mbuf   = (float*)carve((size_t)N * H * 4);
  float* invdeg = (float*)carve((size_t)N * 4);
  float* enbuf  = (float*)carve((size_t)N * 4);
  float* qstar  = (float*)carve((size_t)B * 2 * H * 4);
  float* hsbuf  = (float*)carve((size_t)B * H * 4);
  float* csbuf  = (float*)carve((size_t)B * H * 4);
  int*   gstart = (int*)carve((size_t)B * 4);
  int*   gend   = (int*)carve((size_t)B * 4);

  dim3 b256(256);
  // degree -> inv
  fill_u32_k<<<dim3(64), b256, 0, stream>>>((uint32_t*)invdeg, 0u, N);
  count_deg_k<<<dim3((E + 255) / 256), b256, 0, stream>>>(dst, invdeg, E);
  inv_deg_k<<<dim3((N + 255) / 256), b256, 0, stream>>>(invdeg, N);
  // lin0 -> bufA
  lin0_k<<<dim3((N + 3) / 4), b256, 0, stream>>>(x, lin0_w, lin0_b, bufA, N);
  // edge MLP layer 1 -> u row-major
  edge_mlp1_k<<<dim3((E + 63) / 64), dim3(128), 0, stream>>>(edge_attr, nn_w1, nn_b1, u_rm, E);
  // pack A and B fragments (split-bf16)
  pack_u_k<<<dim3((nfrag_u * 64 + 255) / 256), b256, 0, stream>>>(u_rm, upk_hi, upk_lo, E, nfrag_u);
  pack_w2_k<<<dim3(256), b256, 0, stream>>>(nn_w2, wpk_hi, wpk_lo);

  float* cur = bufA;
  float* nxt = bufB;
  for (int it = 0; it < 3; ++it) {
    fill_u32_k<<<dim3(1024), b256, 0, stream>>>((uint32_t*)agg, 0u, (long long)N * H);
    fused_msg_k<<<dim3((E + TE_WG - 1) / TE_WG), b256, 0, stream>>>(
        upk_hi, upk_lo, wpk_hi, wpk_lo, cur, src, dst, invdeg, nn_b2, agg, E);
    conv_m_k<<<dim3((N + 3) / 4), b256, 0, stream>>>(agg, cur, conv_root, conv_bias, mbuf, N);
    gru_k<<<dim3((N + 15) / 16), dim3(192), 0, stream>>>(mbuf, cur, gru_wih, gru_whh, gru_bih, gru_bhh, nxt, N);
    float* tmp = cur; cur = nxt; nxt = tmp;
  }
  // Set2Set
  fill_u32_k<<<dim3(16), b256, 0, stream>>>((uint32_t*)qstar, 0u, (long long)B * 2 * H);
  fill_u32_k<<<dim3(4), b256, 0, stream>>>((uint32_t*)hsbuf, 0u, (long long)B * H);
  fill_u32_k<<<dim3(4), b256, 0, stream>>>((uint32_t*)csbuf, 0u, (long long)B * H);
  fill_u32_k<<<dim3(1), b256, 0, stream>>>((uint32_t*)gstart, (uint32_t)N, B);
  fill_u32_k<<<dim3(1), b256, 0, stream>>>((uint32_t*)gend, 0u, B);
  graph_ranges_k<<<dim3((N + 255) / 256), b256, 0, stream>>>(batch, gstart, gend, N);
  for (int s = 0; s < 3; ++s) {
    lstm_k<<<dim3(B), b256, 0, stream>>>(qstar, hsbuf, csbuf, lstm_wih, lstm_whh, lstm_bih, lstm_bhh);
    attn_k<<<dim3(B), b256, 0, stream>>>(cur, hsbuf, gstart, gend, enbuf, qstar);
  }
  final_k<<<dim3(B), dim3(64), 0, stream>>>(qstar, lin1_w, lin1_b, lin2_w, lin2_b, (float*)d_out);
}